// Round 5
// baseline (65.312 us; speedup 1.0000x reference)
//
#include <hip/hip_runtime.h>
#include <hip/hip_bf16.h>

#define KDIM  1024
#define NOUT  1024
#define NTOK  8192
#define NCB   16

typedef __attribute__((ext_vector_type(8))) short short8;
typedef __attribute__((ext_vector_type(4))) float f32x4;

__device__ static inline unsigned short f2bf(float f) {
    unsigned int u = __float_as_uint(f);
    return (unsigned short)((u + 0x7FFFu + ((u >> 16) & 1u)) >> 16);
}

__device__ static inline float bf2f(unsigned int h) {
    return __uint_as_float(h << 16);
}

__device__ static inline void async_copy16(const void* g, void* l) {
    __builtin_amdgcn_global_load_lds(
        (const __attribute__((address_space(1))) void*)g,
        (__attribute__((address_space(3))) void*)l, 16, 0, 0);
}

// ---- x fp32 [8192][1024] -> bf16 A [8192][1024] (coalesced) ----
__global__ __launch_bounds__(256) void conv_x_kernel(const float* __restrict__ x,
                                                     unsigned short* __restrict__ A) {
    int u = blockIdx.x * 256 + threadIdx.x;
    const float* src = x + (size_t)u * 8;
    float4 v0 = *(const float4*)(src);
    float4 v1 = *(const float4*)(src + 4);
    short8 o;
    o[0] = (short)f2bf(v0.x); o[1] = (short)f2bf(v0.y);
    o[2] = (short)f2bf(v0.z); o[3] = (short)f2bf(v0.w);
    o[4] = (short)f2bf(v1.x); o[5] = (short)f2bf(v1.y);
    o[6] = (short)f2bf(v1.z); o[7] = (short)f2bf(v1.w);
    *(short8*)(A + (size_t)u * 8) = o;
}

// ---- weight fp32 [16][1024][64] -> bf16 Bt [n=1024][k=1024], n = h*64+o ----
__global__ __launch_bounds__(256) void conv_w_kernel(const float* __restrict__ W,
                                                     unsigned short* __restrict__ Bt) {
    int u = blockIdx.x * 256 + threadIdx.x;
    int n  = u & (NOUT - 1);
    int k0 = (u >> 10) << 3;
    int h = n >> 6, o = n & 63;
    const float* src = W + (size_t)h * KDIM * 64 + o;
    short8 v;
#pragma unroll
    for (int j = 0; j < 8; ++j)
        v[j] = (short)f2bf(src[(size_t)(k0 + j) * 64]);
    *(short8*)(Bt + (size_t)n * KDIM + k0) = v;
}

// ---- B-stationary, zero-loop-barrier GEMM ----
// Block: 512 threads (8 waves). B n-panel [64][1024] bf16 resident in LDS
// (staged once, chunk-XOR swizzled, ONE barrier). Wave w streams A rows
// [m0+w*64, +64) global->VGPR with a 2-deep k prefetch; no __syncthreads in
// the K-loop, so loads pipeline across iterations.
// XCD remap: all 16 n-panels of an m-chunk + 2 m-chunks live on one XCD ->
// A re-reads are XCD-L2 hits (2MB working set).
__global__ __launch_bounds__(512, 2) void gemm_bstat_kernel(const unsigned short* __restrict__ A,
                                                            const unsigned short* __restrict__ Bt,
                                                            unsigned short* __restrict__ Y) {
    extern __shared__ unsigned short Blds[];   // [64 rows][1024 k], swizzled, 128 KB

    const int id  = blockIdx.x;
    const int xcd = id & 7;
    const int j   = id >> 3;                   // 0..31
    const int m0  = (xcd * 2 + (j >> 4)) * 512;
    const int n0  = (j & 15) * 64;

    const int tid  = threadIdx.x;
    const int lane = tid & 63;
    const int w    = tid >> 6;
    const int r15  = lane & 15;
    const int q    = lane >> 4;                // 0..3 (k-chunk within 32)
    const int kq   = q * 8;

    // ---- stage B panel once; dest linear, source carries inverse swizzle ----
#pragma unroll
    for (int i = 0; i < 16; ++i) {
        int slot = i * 512 + tid;              // 16B units, 0..8191
        int row  = slot >> 7;                  // 0..63
        int cd   = slot & 127;                 // dest chunk
        int cs   = cd ^ (row & 7);             // source chunk (involution)
        async_copy16(Bt + (size_t)(n0 + row) * KDIM + cs * 8, Blds + slot * 8);
    }
    __syncthreads();                           // the ONLY barrier

    const unsigned short* Aw = A + (size_t)(m0 + w * 64 + r15) * KDIM + kq;

    f32x4 acc[4][4];
#pragma unroll
    for (int mf = 0; mf < 4; ++mf)
#pragma unroll
        for (int nf = 0; nf < 4; ++nf)
            acc[mf][nf] = (f32x4){0.f, 0.f, 0.f, 0.f};

    short8 a0[4], a1[4];
#pragma unroll
    for (int mf = 0; mf < 4; ++mf) a0[mf] = *(const short8*)(Aw + mf * 16 * KDIM);
#pragma unroll
    for (int mf = 0; mf < 4; ++mf) a1[mf] = *(const short8*)(Aw + mf * 16 * KDIM + 32);

#pragma unroll
    for (int tt = 0; tt < 16; ++tt) {
        // ---- even half: kt = tt*64, consumes a0, prefetches a0(kt+64) ----
        {
            const int c = 8 * tt + q;          // logical chunk = (kt+kq)/8
            short8 bf[4];
#pragma unroll
            for (int nf = 0; nf < 4; ++nf) {
                int ra = nf * 16 + r15;
                bf[nf] = *(const short8*)&Blds[ra * KDIM + ((c ^ (ra & 7)) << 3)];
            }
#pragma unroll
            for (int mf = 0; mf < 4; ++mf)
#pragma unroll
                for (int nf = 0; nf < 4; ++nf)
                    acc[mf][nf] = __builtin_amdgcn_mfma_f32_16x16x32_bf16(a0[mf], bf[nf], acc[mf][nf], 0, 0, 0);
            if (tt < 15) {
#pragma unroll
                for (int mf = 0; mf < 4; ++mf)
                    a0[mf] = *(const short8*)(Aw + mf * 16 * KDIM + (tt + 1) * 64);
            }
        }
        // ---- odd half: kt = tt*64+32, consumes a1, prefetches a1(kt+96) ----
        {
            const int c = 8 * tt + 4 + q;
            short8 bf[4];
#pragma unroll
            for (int nf = 0; nf < 4; ++nf) {
                int ra = nf * 16 + r15;
                bf[nf] = *(const short8*)&Blds[ra * KDIM + ((c ^ (ra & 7)) << 3)];
            }
#pragma unroll
            for (int mf = 0; mf < 4; ++mf)
#pragma unroll
                for (int nf = 0; nf < 4; ++nf)
                    acc[mf][nf] = __builtin_amdgcn_mfma_f32_16x16x32_bf16(a1[mf], bf[nf], acc[mf][nf], 0, 0, 0);
            if (tt < 15) {
#pragma unroll
                for (int mf = 0; mf < 4; ++mf)
                    a1[mf] = *(const short8*)(Aw + mf * 16 * KDIM + (tt + 1) * 64 + 32);
            }
        }
    }

    // write back: D layout col=lane&15, row=(lane>>4)*4+r
#pragma unroll
    for (int mf = 0; mf < 4; ++mf) {
#pragma unroll
        for (int nf = 0; nf < 4; ++nf) {
            int col = n0 + nf * 16 + r15;
#pragma unroll
            for (int r = 0; r < 4; ++r) {
                int row = m0 + w * 64 + mf * 16 + q * 4 + r;
                Y[(size_t)row * NOUT + col] = f2bf(acc[mf][nf][r]);
            }
        }
    }
}

// ---- epilogue: outer product + mean*sqrt(h) + rms_norm; 1 block/token ----
__global__ __launch_bounds__(256) void epilogue_kernel(const unsigned short* __restrict__ Y,
                                                       float* __restrict__ out) {
    __shared__ float ylds[1024];
    __shared__ float red[4];

    const int t = blockIdx.x;
    const int tid = threadIdx.x;
    const unsigned short* yrow = Y + (size_t)t * NOUT;

    {
        uint2 raw = *(const uint2*)(yrow + tid * 4);
        ylds[tid * 4 + 0] = bf2f(raw.x & 0xffffu);
        ylds[tid * 4 + 1] = bf2f(raw.x >> 16);
        ylds[tid * 4 + 2] = bf2f(raw.y & 0xffffu);
        ylds[tid * 4 + 3] = bf2f(raw.y >> 16);
    }
    __syncthreads();

    const int j = tid >> 3;
    const int k0 = (tid & 7) * 4;

    float o0 = 0.f, o1 = 0.f, o2 = 0.f, o3 = 0.f;
#pragma unroll
    for (int h = 0; h < NCB; ++h) {
        float a = ylds[h * 64 + j];
        float4 bb = *(const float4*)&ylds[h * 64 + 32 + k0];
        o0 += a * bb.x; o1 += a * bb.y; o2 += a * bb.z; o3 += a * bb.w;
    }
    o0 *= 0.25f; o1 *= 0.25f; o2 *= 0.25f; o3 *= 0.25f;

    float ss = o0 * o0 + o1 * o1 + o2 * o2 + o3 * o3;
#pragma unroll
    for (int off = 32; off >= 1; off >>= 1)
        ss += __shfl_xor(ss, off, 64);

    const int lane = tid & 63, wv = tid >> 6;
    if (lane == 0) red[wv] = ss;
    __syncthreads();
    float tot = red[0] + red[1] + red[2] + red[3];
    float scale = rsqrtf(tot * (1.0f / 1024.0f) + 1e-12f);

    float4 o;
    o.x = o0 * scale; o.y = o1 * scale; o.z = o2 * scale; o.w = o3 * scale;
    *(float4*)(out + (size_t)t * 1024 + tid * 4) = o;
}

extern "C" void kernel_launch(void* const* d_in, const int* in_sizes, int n_in,
                              void* d_out, int out_size, void* d_ws, size_t ws_size,
                              hipStream_t stream) {
    const float* x   = (const float*)d_in[0];
    const float* wgt = (const float*)d_in[1];
    float* out = (float*)d_out;

    unsigned short* A  = (unsigned short*)d_ws;                        // 16 MB
    unsigned short* Bt = (unsigned short*)((char*)d_ws + (16u << 20)); //  2 MB
    unsigned short* Y  = (unsigned short*)((char*)d_ws + (18u << 20)); // 16 MB

    (void)hipFuncSetAttribute((const void*)gemm_bstat_kernel,
                              hipFuncAttributeMaxDynamicSharedMemorySize, 131072);

    conv_x_kernel<<<NTOK * KDIM / 8 / 256, 256, 0, stream>>>(x, A);
    conv_w_kernel<<<NOUT * KDIM / 8 / 256, 256, 0, stream>>>(wgt, Bt);
    gemm_bstat_kernel<<<256, 512, 131072, stream>>>(A, Bt, Y);
    epilogue_kernel<<<NTOK, 256, 0, stream>>>(Y, out);
}

// Round 6
// 49.941 us; speedup vs baseline: 1.3078x; 1.3078x over previous
//
#include <hip/hip_runtime.h>
#include <hip/hip_bf16.h>

#define KDIM  1024
#define NOUT  1024
#define NTOK  8192
#define NCB   16
#define BM    256
#define BN    128
#define BK    64
#define BUFSZ 49152   // A 32KB + B 16KB per K-tile buffer
#define NBUF  3

typedef __attribute__((ext_vector_type(8))) short short8;
typedef __attribute__((ext_vector_type(4))) float f32x4;

__device__ static inline unsigned short f2bf(float f) {
    unsigned int u = __float_as_uint(f);
    return (unsigned short)((u + 0x7FFFu + ((u >> 16) & 1u)) >> 16);
}

__device__ static inline float bf2f(unsigned int h) {
    return __uint_as_float(h << 16);
}

__device__ static inline void async_copy16(const void* g, void* l) {
    __builtin_amdgcn_global_load_lds(
        (const __attribute__((address_space(1))) void*)g,
        (__attribute__((address_space(3))) void*)l, 16, 0, 0);
}

// ---- x fp32 [8192][1024] -> bf16 A [8192][1024] ----
__global__ __launch_bounds__(256) void conv_x_kernel(const float* __restrict__ x,
                                                     unsigned short* __restrict__ A) {
    int u = blockIdx.x * 256 + threadIdx.x;
    const float* src = x + (size_t)u * 8;
    float4 v0 = *(const float4*)(src);
    float4 v1 = *(const float4*)(src + 4);
    short8 o;
    o[0] = (short)f2bf(v0.x); o[1] = (short)f2bf(v0.y);
    o[2] = (short)f2bf(v0.z); o[3] = (short)f2bf(v0.w);
    o[4] = (short)f2bf(v1.x); o[5] = (short)f2bf(v1.y);
    o[6] = (short)f2bf(v1.z); o[7] = (short)f2bf(v1.w);
    *(short8*)(A + (size_t)u * 8) = o;
}

// ---- weight fp32 [16][1024][64] -> bf16 Bt [n=1024][k=1024], n = h*64+o ----
__global__ __launch_bounds__(256) void conv_w_kernel(const float* __restrict__ W,
                                                     unsigned short* __restrict__ Bt) {
    int u = blockIdx.x * 256 + threadIdx.x;
    int n  = u & (NOUT - 1);
    int k0 = (u >> 10) << 3;
    int h = n >> 6, o = n & 63;
    const float* src = W + (size_t)h * KDIM * 64 + o;
    short8 v;
#pragma unroll
    for (int j = 0; j < 8; ++j)
        v[j] = (short)f2bf(src[(size_t)(k0 + j) * 64]);
    *(short8*)(Bt + (size_t)n * KDIM + k0) = v;
}

// stage one K-tile: A 256x64 (2048 16B slots) + B 128x64 (1024 slots).
// LDS dest linear (wave-uniform base + lane*16); XOR chunk-swizzle carried in
// the per-lane GLOBAL source address (c_src = c_dest ^ (row&7), involution).
__device__ __forceinline__ void stage_tile(const unsigned short* __restrict__ A,
                                           const unsigned short* __restrict__ Bt,
                                           char* lbase, int tid, int m0, int n0, int kel) {
    unsigned short* Al = (unsigned short*)lbase;
    unsigned short* Bl = (unsigned short*)(lbase + 32768);
#pragma unroll
    for (int i = 0; i < 4; ++i) {
        int s = i * 512 + tid;
        int row = s >> 3;
        int cs = (s & 7) ^ (row & 7);
        async_copy16(A + (size_t)(m0 + row) * KDIM + kel + cs * 8, Al + s * 8);
    }
#pragma unroll
    for (int i = 0; i < 2; ++i) {
        int s = i * 512 + tid;
        int row = s >> 3;
        int cs = (s & 7) ^ (row & 7);
        async_copy16(Bt + (size_t)(n0 + row) * KDIM + kel + cs * 8, Bl + s * 8);
    }
}

// one pipelined K-step: stage(kt+2) -> vmcnt(VM) -> bar -> ds_read frags ->
// lgkmcnt(0) -> bar -> setprio(1) 32 MFMA setprio(0).  VM=12 keeps 2 tiles in
// flight (6 loads/thread/tile); never drains to 0 in the main loop.
template <int VM, bool DO_STAGE>
__device__ __forceinline__ void gemm_step(const unsigned short* __restrict__ A,
                                          const unsigned short* __restrict__ Bt,
                                          char* lds, int tid, int m0, int n0, int kt,
                                          int wm, int wn, int r15, int q,
                                          f32x4 (&acc)[4][4]) {
    if (DO_STAGE)
        stage_tile(A, Bt, lds + ((kt + 2) % NBUF) * BUFSZ, tid, m0, n0, (kt + 2) * BK);
    asm volatile("s_waitcnt vmcnt(%0)" :: "i"(VM) : "memory");
    __builtin_amdgcn_sched_barrier(0);
    __builtin_amdgcn_s_barrier();

    const unsigned short* Al = (const unsigned short*)(lds + (kt % NBUF) * BUFSZ);
    const unsigned short* Bl = (const unsigned short*)(lds + (kt % NBUF) * BUFSZ + 32768);
    short8 af[4][2], bf[4][2];
#pragma unroll
    for (int mf = 0; mf < 4; ++mf)
#pragma unroll
        for (int kk = 0; kk < 2; ++kk) {
            int row = wm * 64 + mf * 16 + r15;
            int c = kk * 4 + q;
            af[mf][kk] = *(const short8*)(Al + row * 64 + ((c ^ (row & 7)) << 3));
        }
#pragma unroll
    for (int nf = 0; nf < 4; ++nf)
#pragma unroll
        for (int kk = 0; kk < 2; ++kk) {
            int row = wn * 64 + nf * 16 + r15;
            int c = kk * 4 + q;
            bf[nf][kk] = *(const short8*)(Bl + row * 64 + ((c ^ (row & 7)) << 3));
        }
    asm volatile("s_waitcnt lgkmcnt(0)" ::: "memory");
    __builtin_amdgcn_sched_barrier(0);
    __builtin_amdgcn_s_barrier();   // LDS buffer now reusable by stage(kt+3)

    __builtin_amdgcn_s_setprio(1);
#pragma unroll
    for (int kk = 0; kk < 2; ++kk)
#pragma unroll
        for (int mf = 0; mf < 4; ++mf)
#pragma unroll
            for (int nf = 0; nf < 4; ++nf)
                acc[mf][nf] = __builtin_amdgcn_mfma_f32_16x16x32_bf16(af[mf][kk], bf[nf][kk], acc[mf][nf], 0, 0, 0);
    __builtin_amdgcn_s_setprio(0);
}

// ---- GEMM: Y[m][n] = sum_k A[m][k]*Bt[n][k]; BM=256 BN=128, 8 waves (4x2),
// 3-buffer counted-vmcnt pipeline, XCD remap (8 n-blocks of an m-panel share
// one XCD's L2: per-XCD working set A 2MB + Bt 2MB). ----
__global__ __launch_bounds__(512, 2) void gemm_kernel(const unsigned short* __restrict__ A,
                                                      const unsigned short* __restrict__ Bt,
                                                      unsigned short* __restrict__ Y) {
    extern __shared__ char lds[];   // 3 * 48KB

    const int id  = blockIdx.x;
    const int xcd = id & 7;
    const int j   = id >> 3;                  // 0..31
    const int m0  = (xcd * 4 + (j >> 3)) * BM;
    const int n0  = (j & 7) * BN;

    const int tid  = threadIdx.x;
    const int lane = tid & 63;
    const int w    = tid >> 6;
    const int wm   = w >> 1;                  // 0..3
    const int wn   = w & 1;                   // 0..1
    const int r15  = lane & 15;
    const int q    = lane >> 4;               // 0..3

    f32x4 acc[4][4];
#pragma unroll
    for (int mf = 0; mf < 4; ++mf)
#pragma unroll
        for (int nf = 0; nf < 4; ++nf)
            acc[mf][nf] = (f32x4){0.f, 0.f, 0.f, 0.f};

    // prologue: tiles 0 and 1 in flight
    stage_tile(A, Bt, lds,         tid, m0, n0, 0);
    stage_tile(A, Bt, lds + BUFSZ, tid, m0, n0, BK);

    for (int kt = 0; kt < 14; ++kt)
        gemm_step<12, true>(A, Bt, lds, tid, m0, n0, kt, wm, wn, r15, q, acc);
    gemm_step<6, false>(A, Bt, lds, tid, m0, n0, 14, wm, wn, r15, q, acc);
    gemm_step<0, false>(A, Bt, lds, tid, m0, n0, 15, wm, wn, r15, q, acc);

    // write back: D layout col=lane&15, row=(lane>>4)*4+r
#pragma unroll
    for (int mf = 0; mf < 4; ++mf)
#pragma unroll
        for (int nf = 0; nf < 4; ++nf) {
            int col = n0 + wn * 64 + nf * 16 + r15;
#pragma unroll
            for (int r = 0; r < 4; ++r) {
                int row = m0 + wm * 64 + mf * 16 + q * 4 + r;
                Y[(size_t)row * NOUT + col] = f2bf(acc[mf][nf][r]);
            }
        }
}

// ---- epilogue: outer product + mean*sqrt(h) + rms_norm; 1 block/token ----
__global__ __launch_bounds__(256) void epilogue_kernel(const unsigned short* __restrict__ Y,
                                                       float* __restrict__ out) {
    __shared__ float ylds[1024];
    __shared__ float red[4];

    const int t = blockIdx.x;
    const int tid = threadIdx.x;
    const unsigned short* yrow = Y + (size_t)t * NOUT;

    {
        uint2 raw = *(const uint2*)(yrow + tid * 4);
        ylds[tid * 4 + 0] = bf2f(raw.x & 0xffffu);
        ylds[tid * 4 + 1] = bf2f(raw.x >> 16);
        ylds[tid * 4 + 2] = bf2f(raw.y & 0xffffu);
        ylds[tid * 4 + 3] = bf2f(raw.y >> 16);
    }
    __syncthreads();

    const int jj = tid >> 3;
    const int k0 = (tid & 7) * 4;

    float o0 = 0.f, o1 = 0.f, o2 = 0.f, o3 = 0.f;
#pragma unroll
    for (int h = 0; h < NCB; ++h) {
        float a = ylds[h * 64 + jj];
        float4 bb = *(const float4*)&ylds[h * 64 + 32 + k0];
        o0 += a * bb.x; o1 += a * bb.y; o2 += a * bb.z; o3 += a * bb.w;
    }
    o0 *= 0.25f; o1 *= 0.25f; o2 *= 0.25f; o3 *= 0.25f;

    float ss = o0 * o0 + o1 * o1 + o2 * o2 + o3 * o3;
#pragma unroll
    for (int off = 32; off >= 1; off >>= 1)
        ss += __shfl_xor(ss, off, 64);

    const int lane = tid & 63, wv = tid >> 6;
    if (lane == 0) red[wv] = ss;
    __syncthreads();
    float tot = red[0] + red[1] + red[2] + red[3];
    float scale = rsqrtf(tot * (1.0f / 1024.0f) + 1e-12f);

    float4 o;
    o.x = o0 * scale; o.y = o1 * scale; o.z = o2 * scale; o.w = o3 * scale;
    *(float4*)(out + (size_t)t * 1024 + tid * 4) = o;
}

extern "C" void kernel_launch(void* const* d_in, const int* in_sizes, int n_in,
                              void* d_out, int out_size, void* d_ws, size_t ws_size,
                              hipStream_t stream) {
    const float* x   = (const float*)d_in[0];
    const float* wgt = (const float*)d_in[1];
    float* out = (float*)d_out;

    unsigned short* A  = (unsigned short*)d_ws;                        // 16 MB
    unsigned short* Bt = (unsigned short*)((char*)d_ws + (16u << 20)); //  2 MB
    unsigned short* Y  = (unsigned short*)((char*)d_ws + (18u << 20)); // 16 MB

    (void)hipFuncSetAttribute((const void*)gemm_kernel,
                              hipFuncAttributeMaxDynamicSharedMemorySize, NBUF * BUFSZ);

    conv_x_kernel<<<NTOK * KDIM / 8 / 256, 256, 0, stream>>>(x, A);
    conv_w_kernel<<<NOUT * KDIM / 8 / 256, 256, 0, stream>>>(wgt, Bt);
    gemm_kernel<<<(NTOK / BM) * (NOUT / BN), 512, NBUF * BUFSZ, stream>>>(A, Bt, Y);
    epilogue_kernel<<<NTOK, 256, 0, stream>>>(Y, out);
}